// Round 13
// baseline (114.387 us; speedup 1.0000x reference)
//
#include <hip/hip_runtime.h>
#include <hip/hip_bf16.h>
#include <math.h>

typedef _Float16 half8 __attribute__((ext_vector_type(8)));
typedef _Float16 half4v __attribute__((ext_vector_type(4)));
typedef __fp16 fp16x2 __attribute__((ext_vector_type(2)));
typedef float f32x4 __attribute__((ext_vector_type(4)));
typedef float f32x16 __attribute__((ext_vector_type(16)));

#define D 128
#define SQ 8192
#define SKV 8192
#define BQ 128    // q-rows per block (4 waves x 32)
#define BKV 32
#define LOG2E 1.4426950408889634f
#define DEFER_THR 11.5417f   // 8 * log2(e); P <= 2^11.54 ~ 2981 < f16 max

__device__ __forceinline__ ushort f2bf(float x) {
  union { float f; unsigned u; } v; v.f = x;
  unsigned r = v.u + 0x7fffu + ((v.u >> 16) & 1u);
  return (ushort)(r >> 16);
}
__device__ __forceinline__ float bf2f(ushort h) {
  union { unsigned u; float f; } v; v.u = ((unsigned)h) << 16;
  return v.f;
}
__device__ __forceinline__ unsigned cvtpk_bf(float a, float b) {
  unsigned r;
  asm("v_cvt_pk_bf16_f32 %0, %1, %2" : "=v"(r) : "v"(a), "v"(b));
  return r;
}
__device__ __forceinline__ unsigned cvtpk_h(float a, float b) {
  union { fp16x2 h; unsigned u; } r;
  r.h = __builtin_amdgcn_cvt_pkrtz(a, b);
  return r.u;
}
__device__ __forceinline__ float fexp2(float x) {
  float r;
  asm("v_exp_f32 %0, %1" : "=v"(r) : "v"(x));
  return r;
}
__device__ __forceinline__ void pl32swap(unsigned& a, unsigned& b) {
  asm("v_permlane32_swap_b32 %0, %1" : "+v"(a), "+v"(b));
}

// q: (D x SQ) f32 -> QT (SQ x D) f16 row-major, scaled by log2e
__global__ void prep_q(const float* __restrict__ src, _Float16* __restrict__ dst) {
  __shared__ float tile[32][33];
  int s0 = blockIdx.x * 32, d0 = blockIdx.y * 32;
  int t = threadIdx.x, g = t >> 5, l = t & 31;
#pragma unroll
  for (int j = 0; j < 4; ++j)
    tile[g * 4 + j][l] = src[(size_t)(d0 + g * 4 + j) * SQ + s0 + l];
  __syncthreads();
#pragma unroll
  for (int j = 0; j < 4; ++j) {
    int sl = g * 4 + j;
    dst[(size_t)(s0 + sl) * D + d0 + l] = (_Float16)(tile[l][sl] * LOG2E);
  }
}

// k: (D x SKV) f32 -> PK packed A-frag order for 32-kv tiles:
// elem = (srow>>5)*4096 + (dcol>>4)*512 + (((dcol>>3)&1)*32 + (srow&31))*8 + (dcol&7)
__global__ void prep_k(const float* __restrict__ src, _Float16* __restrict__ dst) {
  __shared__ float tile[32][33];
  int s0 = blockIdx.x * 32, d0 = blockIdx.y * 32;
  int t = threadIdx.x, g = t >> 5, l = t & 31;
#pragma unroll
  for (int j = 0; j < 4; ++j)
    tile[g * 4 + j][l] = src[(size_t)(d0 + g * 4 + j) * SKV + s0 + l];
  __syncthreads();
#pragma unroll
  for (int j = 0; j < 4; ++j) {
    int srow = s0 + g * 4 + j;
    int dcol = d0 + l;
    size_t elem = (size_t)(srow >> 5) * 4096 + (size_t)(dcol >> 4) * 512 +
                  (((dcol >> 3) & 1) * 32 + (srow & 31)) * 8 + (dcol & 7);
    dst[elem] = (_Float16)tile[l][g * 4 + j];
  }
}

// v: (D x SKV) f32 -> PV packed A-frag order for 32-kv tiles:
// elem = (kv>>5)*4096 + ((drow>>5)*2 + ((kv>>4)&1))*512 + (((kv>>3)&1)*32 + (drow&31))*8 + (kv&7)
__global__ void prep_v(const float* __restrict__ src, _Float16* __restrict__ dst) {
  int i4 = (blockIdx.x * 256 + threadIdx.x) * 4;
  float4 v = *(const float4*)(src + i4);
  int drow = i4 >> 13;          // / SKV
  int kv = i4 & (SKV - 1);
  size_t elem = (size_t)(kv >> 5) * 4096 +
                (size_t)((drow >> 5) * 2 + ((kv >> 4) & 1)) * 512 +
                (((kv >> 3) & 1) * 32 + (drow & 31)) * 8 + (kv & 7);
  half4v o = { (_Float16)v.x, (_Float16)v.y, (_Float16)v.z, (_Float16)v.w };
  *(half4v*)(dst + elem) = o;
}

// Flash, LDS-multicast K/V, BKV=32: 32KB LDS -> 4 independent blocks/CU
// (4 waves/SIMD phase diversity). One barrier per step; K,V double-buffered;
// next-step stage issued at step top (full step to land).
__global__ __launch_bounds__(256, 4)
void flash_fwd(const _Float16* __restrict__ QT, const _Float16* __restrict__ PK,
               const _Float16* __restrict__ PV,
               ushort* __restrict__ Opart, float* __restrict__ Mst,
               float* __restrict__ Lst, int splitLen) {
  __shared__ _Float16 Kl[2][BKV * D];   // 8 KB per buffer
  __shared__ _Float16 Vl[2][BKV * D];   // 8 KB per buffer

  const int tid = threadIdx.x;
  const int w = tid >> 6;
  const int lane = tid & 63;
  const int lc = lane & 31;
  const int hi = lane >> 5;
  const int qb = blockIdx.x;
  const int split = blockIdx.y;
  const int qrow = qb * BQ + w * 32 + lc;

  // Q B-frags (col = q = lc, k-dim = d), pre-scaled by log2e
  half8 qh[8];
#pragma unroll
  for (int ds = 0; ds < 8; ++ds)
    qh[ds] = *(const half8*)(QT + (size_t)qrow * D + ds * 16 + hi * 8);

  f32x16 Ot[4];
#pragma unroll
  for (int dt = 0; dt < 4; ++dt)
#pragma unroll
    for (int e = 0; e < 16; ++e) Ot[dt][e] = 0.f;
  float mrun = -INFINITY, lrun = 0.f;

  const int kvBase = split * splitLen;
  const int nsteps = splitLen / BKV;
  const int tBase = kvBase / BKV;

  // ---- staging: K+V tile = 16 x 1KB chunks, 4 per wave; linear LDS dest ----
#define STAGE(NB, T)                                                          \
  {                                                                           \
    _Pragma("unroll")                                                         \
    for (int j = 0; j < 4; ++j) {                                             \
      int cc = w * 4 + j;                                                     \
      int c8 = cc & 7;                                                        \
      const _Float16* gp = ((cc < 8) ? PK : PV) +                             \
                           (size_t)(T) * (BKV * D) + c8 * 512 + lane * 8;     \
      _Float16* lp = ((cc < 8) ? &Kl[NB][0] : &Vl[NB][0]) + c8 * 512;         \
      __builtin_amdgcn_global_load_lds(                                       \
          (const __attribute__((address_space(1))) unsigned*)gp,              \
          (__attribute__((address_space(3))) unsigned*)lp, 16, 0, 0);         \
    }                                                                         \
  }

  STAGE(0, tBase);
  __syncthreads();
  int cur = 0;

  for (int it = 0; it < nsteps; ++it) {
    const bool more = (it + 1 < nsteps);
    if (more) STAGE(cur ^ 1, tBase + it + 1);   // in flight across whole step

    const _Float16* kb = &Kl[cur][0] + lane * 8;
    const _Float16* vb = &Vl[cur][0] + lane * 8;

    // ---- K frags from LDS + QK MFMAs (single 32x32 S^T tile) ----
    half8 ka[8];
#pragma unroll
    for (int j = 0; j < 8; ++j) ka[j] = *(const half8*)(kb + j * 512);

    f32x16 s0;
#pragma unroll
    for (int e = 0; e < 16; ++e) s0[e] = 0.f;
    __builtin_amdgcn_s_setprio(1);
#pragma unroll
    for (int ds = 0; ds < 8; ++ds)
      s0 = __builtin_amdgcn_mfma_f32_32x32x16_f16(ka[ds], qh[ds], s0, 0, 0, 0);
    __builtin_amdgcn_s_setprio(0);

    // ---- V frags issued now; lgkm latency hides under softmax ----
    half8 va[8];
#pragma unroll
    for (int f = 0; f < 8; ++f) va[f] = *(const half8*)(vb + f * 512);

    // ---- in-register online softmax (exp2 domain), tree reductions ----
    float t4a = fmaxf(fmaxf(s0[0], s0[4]), fmaxf(s0[8], s0[12]));
    float t4b = fmaxf(fmaxf(s0[1], s0[5]), fmaxf(s0[9], s0[13]));
    float t4c = fmaxf(fmaxf(s0[2], s0[6]), fmaxf(s0[10], s0[14]));
    float t4d = fmaxf(fmaxf(s0[3], s0[7]), fmaxf(s0[11], s0[15]));
    float mx = fmaxf(fmaxf(t4a, t4b), fmaxf(t4c, t4d));
    mx = fmaxf(mx, __shfl_xor(mx, 32));

    if (!__all(mx - mrun <= DEFER_THR)) {     // defer-max (T13)
      float mn = fmaxf(mrun, mx);
      float sc = fexp2(mrun - mn);            // first iter: exp2(-inf)=0
      mrun = mn;
      lrun *= sc;
#pragma unroll
      for (int dt = 0; dt < 4; ++dt)
#pragma unroll
        for (int e = 0; e < 16; ++e) Ot[dt][e] *= sc;
    }

#pragma unroll
    for (int e = 0; e < 16; ++e) s0[e] = fexp2(s0[e] - mrun);
    float a4a = (s0[0] + s0[4]) + (s0[8] + s0[12]);
    float a4b = (s0[1] + s0[5]) + (s0[9] + s0[13]);
    float a4c = (s0[2] + s0[6]) + (s0[10] + s0[14]);
    float a4d = (s0[3] + s0[7]) + (s0[11] + s0[15]);
    float lsum = (a4a + a4b) + (a4c + a4d);
    lsum += __shfl_xor(lsum, 32);
    lrun += lsum;

    // ---- P -> f16 B-frags in-register (T12: cvt_pkrtz + permlane32_swap) ----
    unsigned pk[8];
    half8 pb[2];
    union { unsigned u[4]; half8 v; } pbu;
#pragma unroll
    for (int j = 0; j < 8; ++j) pk[j] = cvtpk_h(s0[2 * j], s0[2 * j + 1]);
    pl32swap(pk[0], pk[2]); pl32swap(pk[1], pk[3]);
    pl32swap(pk[4], pk[6]); pl32swap(pk[5], pk[7]);
    pbu.u[0] = pk[0]; pbu.u[1] = pk[1]; pbu.u[2] = pk[2]; pbu.u[3] = pk[3]; pb[0] = pbu.v;
    pbu.u[0] = pk[4]; pbu.u[1] = pk[5]; pbu.u[2] = pk[6]; pbu.u[3] = pk[7]; pb[1] = pbu.v;

    // ---- PV: O^T += V^T P^T (2 k-slices x 4 d-tiles) ----
    __builtin_amdgcn_s_setprio(1);
#pragma unroll
    for (int dt = 0; dt < 4; ++dt) {
      Ot[dt] = __builtin_amdgcn_mfma_f32_32x32x16_f16(va[dt * 2 + 0], pb[0], Ot[dt], 0, 0, 0);
      Ot[dt] = __builtin_amdgcn_mfma_f32_32x32x16_f16(va[dt * 2 + 1], pb[1], Ot[dt], 0, 0, 0);
    }
    __builtin_amdgcn_s_setprio(0);

    __syncthreads();   // staged tile landed; all reads of cur done -> safe swap
    cur ^= 1;
  }

  // ---- epilogue: bf16 partials; d = dt*32 + rg*8 + hi*4 + e ----
  ushort* Op = Opart + (size_t)split * SQ * D + (size_t)qrow * D;
#pragma unroll
  for (int dt = 0; dt < 4; ++dt) {
#pragma unroll
    for (int rg = 0; rg < 4; ++rg) {
      uint2 o2;
      o2.x = cvtpk_bf(Ot[dt][4 * rg + 0], Ot[dt][4 * rg + 1]);
      o2.y = cvtpk_bf(Ot[dt][4 * rg + 2], Ot[dt][4 * rg + 3]);
      *(uint2*)(Op + dt * 32 + rg * 8 + hi * 4) = o2;
    }
  }
  if (hi == 0) {
    Mst[split * SQ + qrow] = mrun;   // log2-domain
    Lst[split * SQ + qrow] = lrun;
  }
}

__global__ void combine(const ushort* __restrict__ Opart, const float* __restrict__ Mst,
                        const float* __restrict__ Lst, float* __restrict__ out, int nsplit) {
  int t4 = (blockIdx.x * 256 + threadIdx.x) * 4;
  int qi = t4 >> 7;
  float M = -INFINITY;
  for (int s = 0; s < nsplit; ++s) M = fmaxf(M, Mst[s * SQ + qi]);
  float n0 = 0.f, n1 = 0.f, n2 = 0.f, n3 = 0.f, den = 0.f;
  for (int s = 0; s < nsplit; ++s) {
    float wgt = fexp2(Mst[s * SQ + qi] - M);
    den += wgt * Lst[s * SQ + qi];
    ushort4 u = *(const ushort4*)(Opart + (size_t)s * SQ * D + t4);
    n0 += wgt * bf2f(u.x); n1 += wgt * bf2f(u.y);
    n2 += wgt * bf2f(u.z); n3 += wgt * bf2f(u.w);
  }
  float inv = 1.0f / den;
  float4 o = { n0 * inv, n1 * inv, n2 * inv, n3 * inv };
  *(float4*)(out + t4) = o;
}

extern "C" void kernel_launch(void* const* d_in, const int* in_sizes, int n_in,
                              void* d_out, int out_size, void* d_ws, size_t ws_size,
                              hipStream_t stream) {
  const float* q = (const float*)d_in[0];
  const float* k = (const float*)d_in[1];
  const float* v = (const float*)d_in[2];
  float* out = (float*)d_out;

  char* ws = (char*)d_ws;
  const size_t mat = (size_t)SQ * D * 2;   // 2 MB per f16 matrix
  _Float16* QT = (_Float16*)(ws);
  _Float16* PK = (_Float16*)(ws + mat);
  _Float16* PV = (_Float16*)(ws + 2 * mat);
  char* rest = ws + 3 * mat;

  const size_t opartSz = (size_t)SQ * D * 2;  // bf16 partials: 2 MB per split
  const size_t statSz  = (size_t)SQ * 4;
  int nsplit = 16;   // grid 64 x 16 = 1024 blocks = exactly 4 resident/CU
  while (nsplit > 1 &&
         3 * mat + (size_t)nsplit * (opartSz + 2 * statSz) > ws_size) nsplit >>= 1;

  ushort* Opart = (ushort*)rest;
  float* Mst = (float*)(rest + (size_t)nsplit * opartSz);
  float* Lst = (float*)(rest + (size_t)nsplit * opartSz + (size_t)nsplit * statSz);

  prep_q<<<dim3(SQ / 32, D / 32), 256, 0, stream>>>(q, QT);
  prep_k<<<dim3(SKV / 32, D / 32), 256, 0, stream>>>(k, PK);
  prep_v<<<(D * SKV) / (256 * 4), 256, 0, stream>>>(v, PV);
  flash_fwd<<<dim3(SQ / BQ, nsplit), 256, 0, stream>>>(QT, PK, PV,
                                                       Opart, Mst, Lst, SKV / nsplit);
  combine<<<(SQ * D) / (256 * 4), 256, 0, stream>>>(Opart, Mst, Lst, out, nsplit);
}

// Round 14
// 78.038 us; speedup vs baseline: 1.4658x; 1.4658x over previous
//
#include <hip/hip_runtime.h>
#include <hip/hip_bf16.h>
#include <math.h>

typedef _Float16 half8 __attribute__((ext_vector_type(8)));
typedef _Float16 half4v __attribute__((ext_vector_type(4)));
typedef __fp16 fp16x2 __attribute__((ext_vector_type(2)));
typedef float f32x4 __attribute__((ext_vector_type(4)));
typedef float f32x16 __attribute__((ext_vector_type(16)));

#define D 128
#define SQ 8192
#define SKV 8192
#define BQ 128    // q-rows per block (4 waves x 32)
#define BKV 64
#define NSPLIT 8
#define LOG2E 1.4426950408889634f
#define DEFER_THR 11.5417f   // 8 * log2(e); P <= 2^11.54 ~ 2981 < f16 max

__device__ __forceinline__ ushort f2bf(float x) {
  union { float f; unsigned u; } v; v.f = x;
  unsigned r = v.u + 0x7fffu + ((v.u >> 16) & 1u);
  return (ushort)(r >> 16);
}
__device__ __forceinline__ float bf2f(ushort h) {
  union { unsigned u; float f; } v; v.u = ((unsigned)h) << 16;
  return v.f;
}
__device__ __forceinline__ unsigned cvtpk_bf(float a, float b) {
  unsigned r;
  asm("v_cvt_pk_bf16_f32 %0, %1, %2" : "=v"(r) : "v"(a), "v"(b));
  return r;
}
__device__ __forceinline__ unsigned cvtpk_h(float a, float b) {
  union { fp16x2 h; unsigned u; } r;
  r.h = __builtin_amdgcn_cvt_pkrtz(a, b);
  return r.u;
}
__device__ __forceinline__ float fexp2(float x) {
  float r;
  asm("v_exp_f32 %0, %1" : "=v"(r) : "v"(x));
  return r;
}
__device__ __forceinline__ void pl32swap(unsigned& a, unsigned& b) {
  asm("v_permlane32_swap_b32 %0, %1" : "+v"(a), "+v"(b));
}

// q: (D x SQ) f32 -> QT (SQ x D) f16 row-major, scaled by log2e
__global__ void prep_q(const float* __restrict__ src, _Float16* __restrict__ dst) {
  __shared__ float tile[32][33];
  int s0 = blockIdx.x * 32, d0 = blockIdx.y * 32;
  int t = threadIdx.x, g = t >> 5, l = t & 31;
#pragma unroll
  for (int j = 0; j < 4; ++j)
    tile[g * 4 + j][l] = src[(size_t)(d0 + g * 4 + j) * SQ + s0 + l];
  __syncthreads();
#pragma unroll
  for (int j = 0; j < 4; ++j) {
    int sl = g * 4 + j;
    dst[(size_t)(s0 + sl) * D + d0 + l] = (_Float16)(tile[l][sl] * LOG2E);
  }
}

// k: (D x SKV) f32 -> PK packed A-frag order (f16), 64-kv tiles:
// elem = (kvt*8 + dcol/16)*512 + (((dcol>>3)&1)*32 + (srow&31))*8 + (dcol&7)
__global__ void prep_k(const float* __restrict__ src, _Float16* __restrict__ dst) {
  __shared__ float tile[32][33];
  int s0 = blockIdx.x * 32, d0 = blockIdx.y * 32;
  int t = threadIdx.x, g = t >> 5, l = t & 31;
#pragma unroll
  for (int j = 0; j < 4; ++j)
    tile[g * 4 + j][l] = src[(size_t)(d0 + g * 4 + j) * SKV + s0 + l];
  __syncthreads();
#pragma unroll
  for (int j = 0; j < 4; ++j) {
    int srow = s0 + g * 4 + j;
    int dcol = d0 + l;
    size_t elem = (size_t)((srow >> 5) * 8 + (dcol >> 4)) * 512 +
                  (((dcol >> 3) & 1) * 32 + (srow & 31)) * 8 + (dcol & 7);
    dst[elem] = (_Float16)tile[l][g * 4 + j];
  }
}

// v: (D x SKV) f32 -> PV packed A-frag order (f16), 64-kv tiles:
// elem = kvb*8192 + ((drow>>5)*4 + ((kv>>4)&3))*512 + (((kv>>3)&1)*32 + (drow&31))*8 + (kv&7)
__global__ void prep_v(const float* __restrict__ src, _Float16* __restrict__ dst) {
  int i4 = (blockIdx.x * 256 + threadIdx.x) * 4;
  float4 v = *(const float4*)(src + i4);
  int drow = i4 >> 13;          // / SKV
  int kv = i4 & (SKV - 1);
  size_t elem = (size_t)(kv >> 6) * 8192 +
                (size_t)((drow >> 5) * 4 + ((kv >> 4) & 3)) * 512 +
                (((kv >> 3) & 1) * 32 + (drow & 31)) * 8 + (kv & 7);
  half4v o = { (_Float16)v.x, (_Float16)v.y, (_Float16)v.z, (_Float16)v.w };
  *(half4v*)(dst + elem) = o;
}

// Flash, LDS-multicast K/V (r11 shape: nsplit=8, BKV=64, 2 blocks/CU, one
// barrier/step) + cross-tile software pipeline: softmax+PV of tile it-1
// (VALU+MFMA) overlap QK of tile it (MFMA). Prev V frags held in registers
// across the barrier; prev S stays in registers.
__global__ __launch_bounds__(256, 2)
void flash_fwd(const _Float16* __restrict__ QT, const _Float16* __restrict__ PK,
               const _Float16* __restrict__ PV,
               ushort* __restrict__ Opart, float* __restrict__ Mst,
               float* __restrict__ Lst, int splitLen) {
  __shared__ _Float16 Kl[2][BKV * D];   // 16 KB per buffer
  __shared__ _Float16 Vl[2][BKV * D];

  const int tid = threadIdx.x;
  const int w = tid >> 6;
  const int lane = tid & 63;
  const int lc = lane & 31;
  const int hi = lane >> 5;
  const int qb = blockIdx.x;
  const int split = blockIdx.y;
  const int qrow = qb * BQ + w * 32 + lc;

  // Q B-frags (col = q = lc, k-dim = d), pre-scaled by log2e
  half8 qh[8];
#pragma unroll
  for (int ds = 0; ds < 8; ++ds)
    qh[ds] = *(const half8*)(QT + (size_t)qrow * D + ds * 16 + hi * 8);

  f32x16 Ot[4];
#pragma unroll
  for (int dt = 0; dt < 4; ++dt)
#pragma unroll
    for (int e = 0; e < 16; ++e) Ot[dt][e] = 0.f;
  float mrun = -INFINITY, lrun = 0.f;

  const int kvBase = split * splitLen;
  const int nsteps = splitLen / BKV;

#define STAGE(NB, KV0)                                                        \
  {                                                                           \
    _Pragma("unroll")                                                         \
    for (int j = 0; j < 8; ++j) {                                             \
      int cblk = w * 8 + j;                                                   \
      int cc = cblk & 15;                                                     \
      const _Float16* gp = ((cblk < 16) ? PK : PV) +                          \
                           (size_t)(KV0) * D + cc * 512 + lane * 8;           \
      _Float16* lp = ((cblk < 16) ? &Kl[NB][0] : &Vl[NB][0]) + cc * 512;      \
      __builtin_amdgcn_global_load_lds(                                       \
          (const __attribute__((address_space(1))) unsigned*)gp,              \
          (__attribute__((address_space(3))) unsigned*)lp, 16, 0, 0);         \
    }                                                                         \
  }

// QK for tile in LDS[NB] -> sD0/sD1 (paired ka reads keep transients small)
#define QK(NB, sD0, sD1)                                                      \
  {                                                                           \
    const _Float16* kb = &Kl[NB][0] + lane * 8;                               \
    _Pragma("unroll")                                                         \
    for (int e = 0; e < 16; ++e) { sD0[e] = 0.f; sD1[e] = 0.f; }              \
    __builtin_amdgcn_s_setprio(1);                                            \
    _Pragma("unroll")                                                         \
    for (int ds = 0; ds < 8; ++ds) {                                          \
      half8 kaA = *(const half8*)(kb + ds * 512);                             \
      half8 kaB = *(const half8*)(kb + (8 + ds) * 512);                       \
      sD0 = __builtin_amdgcn_mfma_f32_32x32x16_f16(kaA, qh[ds], sD0, 0, 0, 0);\
      sD1 = __builtin_amdgcn_mfma_f32_32x32x16_f16(kaB, qh[ds], sD1, 0, 0, 0);\
    }                                                                         \
    __builtin_amdgcn_s_setprio(0);                                            \
  }

// softmax (exp2 domain) + pack + PV for S in s0/s1 with V frags in vaP
#define SMPV(s0, s1, vaP)                                                     \
  {                                                                           \
    float t8[8];                                                              \
    _Pragma("unroll")                                                         \
    for (int e = 0; e < 8; ++e)                                               \
      t8[e] = fmaxf(fmaxf(s0[e], s0[e + 8]), fmaxf(s1[e], s1[e + 8]));        \
    float mx = fmaxf(fmaxf(fmaxf(t8[0], t8[4]), fmaxf(t8[1], t8[5])),         \
                     fmaxf(fmaxf(t8[2], t8[6]), fmaxf(t8[3], t8[7])));        \
    mx = fmaxf(mx, __shfl_xor(mx, 32));                                       \
    if (!__all(mx - mrun <= DEFER_THR)) {                                     \
      float mn = fmaxf(mrun, mx);                                             \
      float sc = fexp2(mrun - mn);                                            \
      mrun = mn;                                                              \
      lrun *= sc;                                                             \
      _Pragma("unroll")                                                       \
      for (int dt = 0; dt < 4; ++dt)                                          \
        _Pragma("unroll")                                                     \
        for (int e = 0; e < 16; ++e) Ot[dt][e] *= sc;                         \
    }                                                                         \
    _Pragma("unroll")                                                         \
    for (int e = 0; e < 16; ++e) {                                            \
      s0[e] = fexp2(s0[e] - mrun);                                            \
      s1[e] = fexp2(s1[e] - mrun);                                            \
    }                                                                         \
    float a8[8];                                                              \
    _Pragma("unroll")                                                         \
    for (int e = 0; e < 8; ++e) a8[e] = (s0[e] + s0[e + 8]) + (s1[e] + s1[e + 8]); \
    float lsum = ((a8[0] + a8[4]) + (a8[1] + a8[5])) +                        \
                 ((a8[2] + a8[6]) + (a8[3] + a8[7]));                         \
    lsum += __shfl_xor(lsum, 32);                                             \
    lrun += lsum;                                                             \
    unsigned pk[8];                                                           \
    half8 pb[4];                                                              \
    union { unsigned u[4]; half8 v; } pbu;                                    \
    _Pragma("unroll")                                                         \
    for (int j = 0; j < 8; ++j) pk[j] = cvtpk_h(s0[2 * j], s0[2 * j + 1]);    \
    pl32swap(pk[0], pk[2]); pl32swap(pk[1], pk[3]);                           \
    pl32swap(pk[4], pk[6]); pl32swap(pk[5], pk[7]);                           \
    pbu.u[0] = pk[0]; pbu.u[1] = pk[1]; pbu.u[2] = pk[2]; pbu.u[3] = pk[3];   \
    pb[0] = pbu.v;                                                            \
    pbu.u[0] = pk[4]; pbu.u[1] = pk[5]; pbu.u[2] = pk[6]; pbu.u[3] = pk[7];   \
    pb[1] = pbu.v;                                                            \
    _Pragma("unroll")                                                         \
    for (int j = 0; j < 8; ++j) pk[j] = cvtpk_h(s1[2 * j], s1[2 * j + 1]);    \
    pl32swap(pk[0], pk[2]); pl32swap(pk[1], pk[3]);                           \
    pl32swap(pk[4], pk[6]); pl32swap(pk[5], pk[7]);                           \
    pbu.u[0] = pk[0]; pbu.u[1] = pk[1]; pbu.u[2] = pk[2]; pbu.u[3] = pk[3];   \
    pb[2] = pbu.v;                                                            \
    pbu.u[0] = pk[4]; pbu.u[1] = pk[5]; pbu.u[2] = pk[6]; pbu.u[3] = pk[7];   \
    pb[3] = pbu.v;                                                            \
    __builtin_amdgcn_s_setprio(1);                                            \
    _Pragma("unroll")                                                         \
    for (int cc = 0; cc < 4; ++cc) {                                          \
      Ot[0] = __builtin_amdgcn_mfma_f32_32x32x16_f16(vaP[0 * 4 + cc], pb[cc], Ot[0], 0, 0, 0); \
      Ot[1] = __builtin_amdgcn_mfma_f32_32x32x16_f16(vaP[1 * 4 + cc], pb[cc], Ot[1], 0, 0, 0); \
      Ot[2] = __builtin_amdgcn_mfma_f32_32x32x16_f16(vaP[2 * 4 + cc], pb[cc], Ot[2], 0, 0, 0); \
      Ot[3] = __builtin_amdgcn_mfma_f32_32x32x16_f16(vaP[3 * 4 + cc], pb[cc], Ot[3], 0, 0, 0); \
    }                                                                         \
    __builtin_amdgcn_s_setprio(0);                                            \
  }

  STAGE(0, kvBase);
  __syncthreads();
  int cur = 0;

  f32x16 sP0, sP1;   // prev tile's S (pipeline state)
  half8 vaP[16];     // prev tile's V frags, held across the barrier

  // ---- peel tile 0: QK + V->regs only (its softmax+PV run next step) ----
  STAGE(1, kvBase + BKV);
  QK(0, sP0, sP1);
  {
    const _Float16* vb = &Vl[0][0] + lane * 8;
#pragma unroll
    for (int f = 0; f < 16; ++f) vaP[f] = *(const half8*)(vb + f * 512);
  }
  __syncthreads();
  cur = 1;

  for (int it = 1; it < nsteps; ++it) {
    const bool more = (it + 1 < nsteps);
    if (more) STAGE(cur ^ 1, kvBase + (it + 1) * BKV);  // full step to land

    // QK of tile it (MFMA) overlaps softmax+PV of tile it-1 (VALU+MFMA)
    f32x16 sN0, sN1;
    QK(cur, sN0, sN1);
    SMPV(sP0, sP1, vaP);

    // pull tile it's V frags into regs (from LDS[cur], before it's recycled)
    {
      const _Float16* vb = &Vl[cur][0] + lane * 8;
#pragma unroll
      for (int f = 0; f < 16; ++f) vaP[f] = *(const half8*)(vb + f * 512);
    }
    sP0 = sN0; sP1 = sN1;

    __syncthreads();   // staged tile landed; all reads of cur done
    cur ^= 1;
  }

  // ---- drain last tile ----
  SMPV(sP0, sP1, vaP);

  // ---- epilogue: bf16 partials; d = dt*32 + rg*8 + hi*4 + e ----
  ushort* Op = Opart + (size_t)split * SQ * D + (size_t)qrow * D;
#pragma unroll
  for (int dt = 0; dt < 4; ++dt) {
#pragma unroll
    for (int rg = 0; rg < 4; ++rg) {
      uint2 o2;
      o2.x = cvtpk_bf(Ot[dt][4 * rg + 0], Ot[dt][4 * rg + 1]);
      o2.y = cvtpk_bf(Ot[dt][4 * rg + 2], Ot[dt][4 * rg + 3]);
      *(uint2*)(Op + dt * 32 + rg * 8 + hi * 4) = o2;
    }
  }
  if (hi == 0) {
    Mst[split * SQ + qrow] = mrun;   // log2-domain
    Lst[split * SQ + qrow] = lrun;
  }
}

__global__ void combine(const ushort* __restrict__ Opart, const float* __restrict__ Mst,
                        const float* __restrict__ Lst, float* __restrict__ out, int nsplit) {
  int t4 = (blockIdx.x * 256 + threadIdx.x) * 4;
  int qi = t4 >> 7;
  float M = -INFINITY;
  for (int s = 0; s < nsplit; ++s) M = fmaxf(M, Mst[s * SQ + qi]);
  float n0 = 0.f, n1 = 0.f, n2 = 0.f, n3 = 0.f, den = 0.f;
  for (int s = 0; s < nsplit; ++s) {
    float wgt = fexp2(Mst[s * SQ + qi] - M);
    den += wgt * Lst[s * SQ + qi];
    ushort4 u = *(const ushort4*)(Opart + (size_t)s * SQ * D + t4);
    n0 += wgt * bf2f(u.x); n1 += wgt * bf2f(u.y);
    n2 += wgt * bf2f(u.z); n3 += wgt * bf2f(u.w);
  }
  float inv = 1.0f / den;
  float4 o = { n0 * inv, n1 * inv, n2 * inv, n3 * inv };
  *(float4*)(out + t4) = o;
}

extern "C" void kernel_launch(void* const* d_in, const int* in_sizes, int n_in,
                              void* d_out, int out_size, void* d_ws, size_t ws_size,
                              hipStream_t stream) {
  const float* q = (const float*)d_in[0];
  const float* k = (const float*)d_in[1];
  const float* v = (const float*)d_in[2];
  float* out = (float*)d_out;

  char* ws = (char*)d_ws;
  const size_t mat = (size_t)SQ * D * 2;   // 2 MB per f16 matrix
  _Float16* QT = (_Float16*)(ws);
  _Float16* PK = (_Float16*)(ws + mat);
  _Float16* PV = (_Float16*)(ws + 2 * mat);
  char* rest = ws + 3 * mat;

  const size_t opartSz = (size_t)SQ * D * 2;  // bf16 partials: 2 MB per split
  const size_t statSz  = (size_t)SQ * 4;
  int nsplit = NSPLIT;   // grid 64 x 8 = 512 blocks = 2 resident/CU
  while (nsplit > 1 &&
         3 * mat + (size_t)nsplit * (opartSz + 2 * statSz) > ws_size) nsplit >>= 1;

  ushort* Opart = (ushort*)rest;
  float* Mst = (float*)(rest + (size_t)nsplit * opartSz);
  float* Lst = (float*)(rest + (size_t)nsplit * opartSz + (size_t)nsplit * statSz);

  prep_q<<<dim3(SQ / 32, D / 32), 256, 0, stream>>>(q, QT);
  prep_k<<<dim3(SKV / 32, D / 32), 256, 0, stream>>>(k, PK);
  prep_v<<<(D * SKV) / (256 * 4), 256, 0, stream>>>(v, PV);
  flash_fwd<<<dim3(SQ / BQ, nsplit), 256, 0, stream>>>(QT, PK, PV,
                                                       Opart, Mst, Lst, SKV / nsplit);
  combine<<<(SQ * D) / (256 * 4), 256, 0, stream>>>(Opart, Mst, Lst, out, nsplit);
}